// Round 4
// baseline (244.195 us; speedup 1.0000x reference)
//
#include <hip/hip_runtime.h>

// z[b,d] = x[b,d] * (1 + sum_{i=1..K} w[i-1,d] * x[b,(d+i) mod D])
// B=8192, D=4096, K=16, fp32. Memory-bound; x (134 MB) is L3-resident,
// so floor ~ write stream (131 MB HBM) + L3 reads => ~35-50 us.
// R2 lesson: [stage -> barrier -> compute -> exit] blocks never overlap
// staging with compute (barrier drains vmcnt(0)); 85 us, VALUBusy 17%.
// R3: persistent double-buffered pipeline -- prefetch tile t+1 async while
// computing tile t; one barrier per tile; prefetch has the whole compute
// phase to land before the drain.

#define D 4096
#define DG 1024          // D/4 float4 column-groups per row
#define K 16
#define TPB 256
#define TILE_B 4         // rows per tile
#define NTILES 8         // tiles per block -> 32 rows per block
#define ROW_F4 260       // 256 groups + 4 halo groups
#define ROW_F (ROW_F4 * 4)

__global__ __launch_bounds__(TPB) void quad_enhancer_kernel(
    const float* __restrict__ x, const float* __restrict__ w,
    float* __restrict__ out) {
  __shared__ float lds[2][TILE_B * ROW_F];  // 2 x 16640 B = 33280 B -> 4 blk/CU

  const int tid = threadIdx.x;
  const int cg0 = blockIdx.x * TPB;
  const int cg = cg0 + tid;
  const float4* x4 = (const float4*)x;
  const float4* w4 = (const float4*)w;
  float4* out4 = (float4*)out;

  // ---- prologue: stage tile 0 into buffer 0 ----
  int b0 = blockIdx.y * (TILE_B * NTILES);
  {
    float4 h0;
    if (tid < TILE_B * 4) {  // halo load first (oldest in vmcnt FIFO)
      h0 = x4[(size_t)(b0 + (tid >> 2)) * DG + ((cg0 + 256 + (tid & 3)) & (DG - 1))];
    }
#pragma unroll
    for (int r = 0; r < TILE_B; ++r) {
      __builtin_amdgcn_global_load_lds(
          (const __attribute__((address_space(1))) void*)&x4[(size_t)(b0 + r) * DG + cg],
          (__attribute__((address_space(3))) void*)&lds[0][r * ROW_F + tid * 4],
          16, 0, 0);
    }
    if (tid < TILE_B * 4) {
      *(float4*)&lds[0][(tid >> 2) * ROW_F + (256 + (tid & 3)) * 4] = h0;
    }
  }

  // w[:, 4cg..4cg+3] in registers (64 VGPR), reused for all 32 rows.
  float4 wv[K];
#pragma unroll
  for (int i = 0; i < K; ++i) wv[i] = w4[i * DG + cg];

  __syncthreads();  // tile 0 staged

#pragma unroll 1
  for (int t = 0; t < NTILES; ++t) {
    const int cur = t & 1;
    const int nb0 = b0 + TILE_B;

    // ---- issue prefetch of tile t+1 into the other buffer (async) ----
    float4 nhalo;
    if (t + 1 < NTILES) {
      if (tid < TILE_B * 4) {  // halo load first: oldest outstanding
        nhalo = x4[(size_t)(nb0 + (tid >> 2)) * DG + ((cg0 + 256 + (tid & 3)) & (DG - 1))];
      }
#pragma unroll
      for (int r = 0; r < TILE_B; ++r) {
        __builtin_amdgcn_global_load_lds(
            (const __attribute__((address_space(1))) void*)&x4[(size_t)(nb0 + r) * DG + cg],
            (__attribute__((address_space(3))) void*)&lds[cur ^ 1][r * ROW_F + tid * 4],
            16, 0, 0);
      }
    }

    // ---- compute tile t from the current buffer ----
#pragma unroll
    for (int r = 0; r < TILE_B; ++r) {
      const float4* lrow = (const float4*)&lds[cur][r * ROW_F];
      float xs[20];
#pragma unroll
      for (int j = 0; j < 5; ++j) {
        float4 v = lrow[tid + j];
        xs[4 * j + 0] = v.x;
        xs[4 * j + 1] = v.y;
        xs[4 * j + 2] = v.z;
        xs[4 * j + 3] = v.w;
      }
      float ax = 1.0f, ay = 1.0f, az = 1.0f, aw = 1.0f;
#pragma unroll
      for (int i = 0; i < K; ++i) {
        ax = fmaf(wv[i].x, xs[i + 1], ax);
        ay = fmaf(wv[i].y, xs[i + 2], ay);
        az = fmaf(wv[i].z, xs[i + 3], az);
        aw = fmaf(wv[i].w, xs[i + 4], aw);
      }
      float4 o;
      o.x = xs[0] * ax;
      o.y = xs[1] * ay;
      o.z = xs[2] * az;
      o.w = xs[3] * aw;
      out4[(size_t)(b0 + r) * DG + cg] = o;
    }

    // halo ds_write: waits only on the halo load (issued before the async
    // LDS loads), which had the whole compute phase to complete.
    if (t + 1 < NTILES) {
      if (tid < TILE_B * 4) {
        *(float4*)&lds[cur ^ 1][(tid >> 2) * ROW_F + (256 + (tid & 3)) * 4] = nhalo;
      }
    }
    __syncthreads();  // protects buffer reuse; drains prefetch (already landed)
    b0 = nb0;
  }
}

extern "C" void kernel_launch(void* const* d_in, const int* in_sizes, int n_in,
                              void* d_out, int out_size, void* d_ws, size_t ws_size,
                              hipStream_t stream) {
  const float* x = (const float*)d_in[0];
  const float* w = (const float*)d_in[1];
  float* out = (float*)d_out;

  dim3 grid(DG / TPB, 8192 / (TILE_B * NTILES));  // (4, 256) = 1024 blocks, 4/CU
  quad_enhancer_kernel<<<grid, TPB, 0, stream>>>(x, w, out);
}